// Round 1
// baseline (334.274 us; speedup 1.0000x reference)
//
#include <hip/hip_runtime.h>

// YOLO loss: S=7, B=2, C=80. preds cell = 90 f32, target cell = 85 f32.
// Output: 4 f32 scalars (coords, obj, noobj, classes), summed over 401408 cells.

#define NPRED 90
#define NTGT  85
#define NCLS  80

__device__ __forceinline__ float sgnf(float x) {
    // matches jnp.sign: sign(0) == 0
    return (x > 0.0f) ? 1.0f : ((x < 0.0f) ? -1.0f : 0.0f);
}

__device__ __forceinline__ float iou_vs_target(
    float acx, float acy, float aw, float ah,
    float bx1, float by1, float bx2, float by2, float area_b)
{
    float ax1 = acx - aw * 0.5f, ay1 = acy - ah * 0.5f;
    float ax2 = acx + aw * 0.5f, ay2 = acy + ah * 0.5f;
    float iw = fmaxf(fminf(ax2, bx2) - fmaxf(ax1, bx1), 0.0f);
    float ih = fmaxf(fminf(ay2, by2) - fmaxf(ay1, by1), 0.0f);
    float inter = iw * ih;
    float area_a = (ax2 - ax1) * (ay2 - ay1);
    return inter / (area_a + area_b - inter);
}

__global__ __launch_bounds__(256) void yolo_loss_kernel(
    const float* __restrict__ preds, const float* __restrict__ targ,
    float* __restrict__ out, int n_cells)
{
    float coords = 0.0f, objl = 0.0f, noobjl = 0.0f, clsl = 0.0f;

    int tid    = blockIdx.x * 256 + threadIdx.x;
    int stride = gridDim.x * 256;

    for (int cell = tid; cell < n_cells; cell += stride) {
        const float* p = preds + (size_t)cell * NPRED;
        const float* t = targ  + (size_t)cell * NTGT;
        // cell*360 % 8 == 0 -> float2 loads of preds are always 8B-aligned
        const float2* p2 = (const float2*)p;

        float obj = t[NCLS];  // t[80]

        // ---- classes loss: sum_k (p[k]*obj - t[k])^2, k in [0,80) ----
        float cls = 0.0f;
        #pragma unroll 10
        for (int k = 0; k < NCLS / 2; ++k) {
            float2 pv = p2[k];
            float d0 = fmaf(pv.x, obj, -t[2 * k]);
            float d1 = fmaf(pv.y, obj, -t[2 * k + 1]);
            cls = fmaf(d0, d0, cls);
            cls = fmaf(d1, d1, cls);
        }
        clsl += cls;

        // ---- box fields ----
        float2 q0 = p2[40];  // p[80], p[81]
        float2 q1 = p2[41];  // p[82], p[83]
        float2 q2 = p2[42];  // p[84], p[85]
        float2 q3 = p2[43];  // p[86], p[87]
        float2 q4 = p2[44];  // p[88], p[89]

        float tcx = t[81], tcy = t[82], tw = t[83], th = t[84];
        float bx1 = tcx - tw * 0.5f, by1 = tcy - th * 0.5f;
        float bx2 = tcx + tw * 0.5f, by2 = tcy + th * 0.5f;
        float area_b = (bx2 - bx1) * (by2 - by1);

        // box1 = p[86..89], box2 = p[81..84]
        float iou1 = iou_vs_target(q3.x, q3.y, q4.x, q4.y, bx1, by1, bx2, by2, area_b);
        float iou2 = iou_vs_target(q0.y, q1.x, q1.y, q2.x, bx1, by1, bx2, by2, area_b);
        bool use2 = iou2 > iou1;  // argmax: tie -> box1

        float pcx = obj * (use2 ? q0.y : q3.x);
        float pw  = obj * (use2 ? q1.y : q4.x);
        float ph  = obj * (use2 ? q2.x : q4.y);

        // center loss uses ONLY cx (ref's [..., :-3] on a 4-vector)
        float dc = pcx - tcx;
        float dw = sgnf(pw) * sqrtf(fabsf(pw) + 1e-6f) - sqrtf(tw);
        float dh = sgnf(ph) * sqrtf(fabsf(ph) + 1e-6f) - sqrtf(th);
        coords = fmaf(dc, dc, coords);
        coords = fmaf(dw, dw, coords);
        coords = fmaf(dh, dh, coords);

        float obj_pred = use2 ? q0.x : q2.y;  // p[80] : p[85]
        float e1 = fmaf(obj, obj_pred, -obj);
        objl = fmaf(e1, e1, objl);
        float e2 = fmaf(1.0f - obj, obj_pred, -obj);
        noobjl = fmaf(e2, e2, noobjl);
    }

    // ---- wave reduce (64 lanes) ----
    #pragma unroll
    for (int off = 32; off > 0; off >>= 1) {
        coords += __shfl_down(coords, off);
        objl   += __shfl_down(objl, off);
        noobjl += __shfl_down(noobjl, off);
        clsl   += __shfl_down(clsl, off);
    }

    __shared__ float red[4][4];  // [value][wave], 256 threads = 4 waves
    int wave = threadIdx.x >> 6;
    int lane = threadIdx.x & 63;
    if (lane == 0) {
        red[0][wave] = coords;
        red[1][wave] = objl;
        red[2][wave] = noobjl;
        red[3][wave] = clsl;
    }
    __syncthreads();
    if (threadIdx.x == 0) {
        float c = red[0][0] + red[0][1] + red[0][2] + red[0][3];
        float o = red[1][0] + red[1][1] + red[1][2] + red[1][3];
        float n = red[2][0] + red[2][1] + red[2][2] + red[2][3];
        float k = red[3][0] + red[3][1] + red[3][2] + red[3][3];
        atomicAdd(&out[0], 5.0f * c);   // LAMBDA_COORDS on center+dims
        atomicAdd(&out[1], o);
        atomicAdd(&out[2], 0.5f * n);   // LAMBDA_NOOBJ
        atomicAdd(&out[3], k);
    }
}

extern "C" void kernel_launch(void* const* d_in, const int* in_sizes, int n_in,
                              void* d_out, int out_size, void* d_ws, size_t ws_size,
                              hipStream_t stream) {
    const float* preds = (const float*)d_in[0];
    const float* targ  = (const float*)d_in[1];
    float* out = (float*)d_out;

    int n_cells = in_sizes[0] / NPRED;  // 8192*7*7 = 401408

    // d_out is poisoned to 0xAA before every timed launch -> zero it on-stream.
    hipMemsetAsync(d_out, 0, (size_t)out_size * sizeof(float), stream);

    int blocks = (n_cells + 255) / 256;
    hipLaunchKernelGGL(yolo_loss_kernel, dim3(blocks), dim3(256), 0, stream,
                       preds, targ, out, n_cells);
}